// Round 3
// baseline (191.166 us; speedup 1.0000x reference)
//
#include <hip/hip_runtime.h>

// Problem dims
#define B_   16
#define C_   256
#define HW_  3136      // 56*56
#define W_   56
#define CR_  128
#define KKG_ 144
#define G_   16
#define NPOS (B_*HW_)  // 50176
#define EPS_ 1e-5f
#define NBLK 784       // 16 b * 49 p-tiles of 64

typedef float f32x4 __attribute__((ext_vector_type(4)));
typedef short s16x8 __attribute__((ext_vector_type(8)));

// ws layout (bytes):
//   t2   : [16 b][3136 p][128 o] bf16 (p-major!) = 12,845,056
//   kern : [16 b][144 o2][3136 p] bf16           = 14,450,688
//   gacc : [256] f32 (sum[128]|sumsq[128])       = 1,024
//   wbfr : [128][256] bf16                       = 65,536
//   wbfs : [144][128] bf16                       = 36,864
#define T2_OFF_B    0
#define KERN_OFF_B  12845056
#define GACC_OFF_B  27295744
#define WBFR_OFF_B  27296768
#define WBFS_OFF_B  27362304

__device__ inline unsigned short f2bf(float f) {
    unsigned u = __float_as_uint(f);
    u += 0x7fff + ((u >> 16) & 1);          // RNE
    return (unsigned short)(u >> 16);
}
__device__ inline float bf2f(unsigned short h) {
    return __uint_as_float(((unsigned)h) << 16);
}
__device__ inline unsigned pk2(float a, float b) {
    return (unsigned)f2bf(a) | ((unsigned)f2bf(b) << 16);
}

// ---------------------------------------------------------------------------
// K0: cast weights to bf16 once + zero the BN accumulator.
// ---------------------------------------------------------------------------
__global__ __launch_bounds__(256) void prep_cast(
    const float* __restrict__ w_reduce, const float* __restrict__ w_span,
    unsigned short* __restrict__ wbfr, unsigned short* __restrict__ wbfs,
    float* __restrict__ gacc)
{
    int idx = blockIdx.x * 256 + threadIdx.x;
    if (idx < 256) gacc[idx] = 0.0f;
    if (idx < 32768) {
        wbfr[idx] = f2bf(w_reduce[idx]);
    } else {
        int k = idx - 32768;
        if (k < 18432) wbfs[k] = f2bf(w_span[k]);
    }
}

// ---------------------------------------------------------------------------
// K1: t2[b][p][o] = sum_c w_reduce[o][c] * x[b][c][p]   (bf16 MFMA 16x16x32)
// Block: 128 o x 64 p (784 blocks, one b each). 4 waves 2x2 over (64o x 32p).
// NO LDS staging, NO inner barriers: A and B fragments loaded directly from
// global with full line utilization:
//   A: wbfr[row=i][c0+q*8..+7] = one dwordx4, q-groups tile the 64B line.
//   B: x[c0+q*8+k][p0+nrow+i]: per load inst 16 px x 4 ch = 4 full lines.
// BN sums accumulated to gacc via f32 atomics (bn_finalize kernel deleted).
// t2 stored p-major so K3 can fragment-load it contiguously.
// ---------------------------------------------------------------------------
__global__ __launch_bounds__(256) void reduce_mfma(
    const float* __restrict__ x, const unsigned short* __restrict__ wbfr,
    unsigned short* __restrict__ t2, float* __restrict__ gacc)
{
    __shared__ float redp[128][2], redq[128][2];

    const int tid = threadIdx.x;
    const int lane = tid & 63, wv = tid >> 6;
    const int q = lane >> 4, i = lane & 15;
    const int mrow = (wv >> 1) * 64, nrow = (wv & 1) * 32;
    const int blk = blockIdx.x;
    const int b = blk / 49;
    const int p0 = (blk % 49) * 64;

    // per-lane bases
    const float* xpl = x + (size_t)b * C_ * HW_ + p0 + nrow + i;
    const unsigned short* wb = wbfr + (size_t)(mrow + i) * C_ + q * 8;

    f32x4 acc[4][2] = {};

    #pragma unroll
    for (int c0 = 0; c0 < C_; c0 += 32) {
        s16x8 af[4];
        #pragma unroll
        for (int mt = 0; mt < 4; mt++)
            af[mt] = *(const s16x8*)(wb + (size_t)mt * 16 * C_ + c0);

        s16x8 bfr[2];
        #pragma unroll
        for (int nt = 0; nt < 2; nt++) {
            const float* xc = xpl + nt * 16;
            union { s16x8 v; unsigned u[4]; } Bv;
            #pragma unroll
            for (int k2 = 0; k2 < 4; k2++) {
                float fa = xc[(size_t)(c0 + q * 8 + 2 * k2) * HW_];
                float fb = xc[(size_t)(c0 + q * 8 + 2 * k2 + 1) * HW_];
                Bv.u[k2] = pk2(fa, fb);
            }
            bfr[nt] = Bv.v;
        }

        #pragma unroll
        for (int mt = 0; mt < 4; mt++)
            #pragma unroll
            for (int nt = 0; nt < 2; nt++)
                acc[mt][nt] = __builtin_amdgcn_mfma_f32_16x16x32_bf16(
                    af[mt], bfr[nt], acc[mt][nt], 0, 0, 0);
    }

    // Epilogue: D col=i -> p, row=q*4+reg -> o (4 consecutive o per lane).
    // Store t2[b][p][o] as one dwordx2 per (mt,nt).
    #pragma unroll
    for (int mt = 0; mt < 4; mt++) {
        #pragma unroll
        for (int nt = 0; nt < 2; nt++) {
            int p = p0 + nrow + nt * 16 + i;
            uint2 pr;
            pr.x = pk2(acc[mt][nt][0], acc[mt][nt][1]);
            pr.y = pk2(acc[mt][nt][2], acc[mt][nt][3]);
            *(uint2*)(t2 + ((size_t)b * HW_ + p) * CR_ + mrow + mt * 16 + q * 4) = pr;
        }
        // BN partials: reduce over p (i lanes + nt), collect per o.
        #pragma unroll
        for (int reg = 0; reg < 4; reg++) {
            float v0 = acc[mt][0][reg], v1 = acc[mt][1][reg];
            float s = v0 + v1;
            float ss = v0 * v0 + v1 * v1;
            #pragma unroll
            for (int m = 1; m < 16; m <<= 1) {
                s  += __shfl_xor(s, m);
                ss += __shfl_xor(ss, m);
            }
            if (i == 0) {
                int o = mrow + mt * 16 + q * 4 + reg;
                redp[o][wv & 1] = s;
                redq[o][wv & 1] = ss;
            }
        }
    }
    __syncthreads();
    if (tid < 128) atomicAdd(&gacc[tid], redp[tid][0] + redp[tid][1]);
    else           atomicAdd(&gacc[tid], redq[tid - 128][0] + redq[tid - 128][1]);
}

// ---------------------------------------------------------------------------
// K3: kern[b][o2][p] = sum_o w_span[o2][o]*relu(bn(t2[b][p][o])) + b_span[o2]
// Block: 144 o2 x 64 p (784 blocks). 4 waves split p 4-way (144 x 16 each).
// NO LDS staging, NO inner barriers. Preamble computes BN scale/shift from
// gacc (redundantly per block — 128 rsqrt, free). B-frag = contiguous
// dwordx4 from p-major t2 + in-reg BN/ReLU using LDS-broadcast float4 tables.
// ---------------------------------------------------------------------------
__global__ __launch_bounds__(256) void span_mfma(
    const unsigned short* __restrict__ t2, const unsigned short* __restrict__ wbfs,
    const float* __restrict__ b_span, const float* __restrict__ gacc,
    const float* __restrict__ gamma, const float* __restrict__ beta,
    unsigned short* __restrict__ kern)
{
    __shared__ __align__(16) float scs[128], shs[128];
    __shared__ float bsp[144];

    const int tid = threadIdx.x;
    const int lane = tid & 63, wv = tid >> 6;
    const int q = lane >> 4, i = lane & 15;
    const int blk = blockIdx.x;
    const int b = blk / 49;
    const int p0 = (blk % 49) * 64;

    if (tid < 128) {
        float s = gacc[tid], ss = gacc[128 + tid];
        const float inv_n = 1.0f / (float)NPOS;
        float mu = s * inv_n;
        float var = ss * inv_n - mu * mu;
        float sc = gamma[tid] * rsqrtf(var + EPS_);
        scs[tid] = sc;
        shs[tid] = beta[tid] - mu * sc;
    }
    if (tid < 144) bsp[tid] = b_span[tid];
    __syncthreads();

    const int p = p0 + wv * 16 + i;
    const unsigned short* tb = t2 + ((size_t)b * HW_ + p) * CR_ + q * 8;
    const unsigned short* wb = wbfs + (size_t)i * CR_ + q * 8;

    f32x4 acc[9] = {};

    #pragma unroll
    for (int c0 = 0; c0 < CR_; c0 += 32) {
        const int cb = c0 + q * 8;
        s16x8 traw = *(const s16x8*)(tb + c0);
        float4 s0 = *(const float4*)&scs[cb];
        float4 s1 = *(const float4*)&scs[cb + 4];
        float4 h0 = *(const float4*)&shs[cb];
        float4 h1 = *(const float4*)&shs[cb + 4];
        float f0 = fmaxf(fmaf(bf2f((unsigned short)traw[0]), s0.x, h0.x), 0.f);
        float f1 = fmaxf(fmaf(bf2f((unsigned short)traw[1]), s0.y, h0.y), 0.f);
        float f2 = fmaxf(fmaf(bf2f((unsigned short)traw[2]), s0.z, h0.z), 0.f);
        float f3 = fmaxf(fmaf(bf2f((unsigned short)traw[3]), s0.w, h0.w), 0.f);
        float f4 = fmaxf(fmaf(bf2f((unsigned short)traw[4]), s1.x, h1.x), 0.f);
        float f5 = fmaxf(fmaf(bf2f((unsigned short)traw[5]), s1.y, h1.y), 0.f);
        float f6 = fmaxf(fmaf(bf2f((unsigned short)traw[6]), s1.z, h1.z), 0.f);
        float f7 = fmaxf(fmaf(bf2f((unsigned short)traw[7]), s1.w, h1.w), 0.f);
        union { s16x8 v; unsigned u[4]; } Bv;
        Bv.u[0] = pk2(f0, f1);
        Bv.u[1] = pk2(f2, f3);
        Bv.u[2] = pk2(f4, f5);
        Bv.u[3] = pk2(f6, f7);

        #pragma unroll
        for (int mt = 0; mt < 9; mt++) {
            s16x8 af = *(const s16x8*)(wb + (size_t)mt * 16 * CR_ + c0);
            acc[mt] = __builtin_amdgcn_mfma_f32_16x16x32_bf16(af, Bv.v, acc[mt], 0, 0, 0);
        }
    }

    // Epilogue: kern[b][o2][p] bf16; col=i -> p, row=q*4+reg -> o2
    #pragma unroll
    for (int mt = 0; mt < 9; mt++) {
        #pragma unroll
        for (int reg = 0; reg < 4; reg++) {
            int o2 = mt * 16 + q * 4 + reg;
            kern[((size_t)b * KKG_ + o2) * HW_ + p] = f2bf(acc[mt][reg] + bsp[o2]);
        }
    }
}

// ---------------------------------------------------------------------------
// K4: out[b, g*16+d, p] = sum_kk x[b, g*16+d, p+off(kk)] * kern[b, kk*16+g, p]
// ---------------------------------------------------------------------------
__global__ __launch_bounds__(256) void involution_apply(
    const float* __restrict__ x, const unsigned short* __restrict__ kern,
    float* __restrict__ out)
{
    int gtid = blockIdx.x * 256 + threadIdx.x;
    int pix = gtid % HW_;
    int bg  = gtid / HW_;
    int g = bg & 15;
    int b = bg >> 4;
    int h = pix / W_;
    int w = pix % W_;

    const unsigned short* kb = kern + (size_t)b * KKG_ * HW_ + pix;
    float kv[9];
    #pragma unroll
    for (int kk = 0; kk < 9; kk++)
        kv[kk] = bf2f(kb[(size_t)(kk * G_ + g) * HW_]);

    float acc[16];
    #pragma unroll
    for (int d = 0; d < 16; d++) acc[d] = 0.0f;

    const float* xb = x + (size_t)(b * C_ + g * 16) * HW_;
    #pragma unroll
    for (int di = 0; di < 3; di++) {
        int hh = h + di - 1;
        if (hh < 0 || hh >= W_) continue;
        #pragma unroll
        for (int dj = 0; dj < 3; dj++) {
            int ww = w + dj - 1;
            if (ww < 0 || ww >= W_) continue;
            float kval = kv[di * 3 + dj];
            int off = hh * W_ + ww;
            #pragma unroll
            for (int d = 0; d < 16; d++)
                acc[d] = fmaf(xb[(size_t)d * HW_ + off], kval, acc[d]);
        }
    }
    float* ob = out + (size_t)(b * C_ + g * 16) * HW_ + pix;
    #pragma unroll
    for (int d = 0; d < 16; d++) ob[(size_t)d * HW_] = acc[d];
}

extern "C" void kernel_launch(void* const* d_in, const int* in_sizes, int n_in,
                              void* d_out, int out_size, void* d_ws, size_t ws_size,
                              hipStream_t stream) {
    const float* x        = (const float*)d_in[0];
    const float* w_reduce = (const float*)d_in[1];
    // d_in[2] = b_reduce: unused — per-channel bias cancels exactly in BN.
    const float* gamma    = (const float*)d_in[3];
    const float* beta     = (const float*)d_in[4];
    const float* w_span   = (const float*)d_in[5];
    const float* b_span   = (const float*)d_in[6];
    float* out = (float*)d_out;

    char* wsb = (char*)d_ws;
    unsigned short* t2   = (unsigned short*)(wsb + T2_OFF_B);
    unsigned short* kern = (unsigned short*)(wsb + KERN_OFF_B);
    float*          gacc = (float*)(wsb + GACC_OFF_B);
    unsigned short* wbfr = (unsigned short*)(wsb + WBFR_OFF_B);
    unsigned short* wbfs = (unsigned short*)(wsb + WBFS_OFF_B);

    prep_cast<<<200, 256, 0, stream>>>(w_reduce, w_span, wbfr, wbfs, gacc);
    reduce_mfma<<<NBLK, 256, 0, stream>>>(x, wbfr, t2, gacc);
    span_mfma<<<NBLK, 256, 0, stream>>>(t2, wbfs, b_span, gacc, gamma, beta, kern);
    involution_apply<<<(B_ * G_ * HW_) / 256, 256, 0, stream>>>(x, kern, out);
}

// Round 4
// 185.266 us; speedup vs baseline: 1.0318x; 1.0318x over previous
//
#include <hip/hip_runtime.h>
#include <hip/hip_bf16.h>

// Problem dims
#define B_   16
#define C_   256
#define HW_  3136      // 56*56
#define W_   56
#define CR_  128
#define KKG_ 144
#define G_   16
#define NPOS (B_*HW_)  // 50176
#define EPS_ 1e-5f
#define NBLK 784       // 16 b * 49 p-tiles of 64

typedef float f32x4 __attribute__((ext_vector_type(4)));
typedef short s16x8 __attribute__((ext_vector_type(8)));

// ws layout (bytes):
//   t2   : [16 b][3136 p][128 o] bf16 (p-major)    = 12,845,056
//   kern : [16 b][16 g][9 kk][3136 p] bf16         = 14,450,688
//   gacc : [256] f32 (sum[128]|sumsq[128])         = 1,024
//   wbfr : [128][256] bf16                         = 65,536
//   wbfs : [144][128] bf16                         = 36,864
#define T2_OFF_B    0
#define KERN_OFF_B  12845056
#define GACC_OFF_B  27295744
#define WBFR_OFF_B  27296768
#define WBFS_OFF_B  27362304

__device__ inline unsigned short f2bf(float f) {
    unsigned u = __float_as_uint(f);
    u += 0x7fff + ((u >> 16) & 1);          // RNE
    return (unsigned short)(u >> 16);
}
__device__ inline float bf2f(unsigned short h) {
    return __uint_as_float(((unsigned)h) << 16);
}
// packed f32 pair -> bf16 pair; compiler lowers to v_cvt_pk_bf16_f32 (RNE)
__device__ inline unsigned pkcvt(float a, float b) {
    float2 f2; f2.x = a; f2.y = b;
    __hip_bfloat162 h = __float22bfloat162_rn(f2);
    union { __hip_bfloat162 h2; unsigned u; } cv; cv.h2 = h;
    return cv.u;
}

// async global->LDS, 16B per lane. lptr must be wave-uniform (HW scatters
// lane L at lptr + L*16); gptr is per-lane.
typedef const __attribute__((address_space(1))) unsigned int* gas_t;
typedef __attribute__((address_space(3))) unsigned int* las_t;
__device__ inline void gload_lds16(const void* g, void* l) {
    __builtin_amdgcn_global_load_lds((gas_t)g, (las_t)l, 16, 0, 0);
}

// ---------------------------------------------------------------------------
// K0: cast weights to bf16 once + zero the BN accumulator.
// ---------------------------------------------------------------------------
__global__ __launch_bounds__(256) void prep_cast(
    const float* __restrict__ w_reduce, const float* __restrict__ w_span,
    unsigned short* __restrict__ wbfr, unsigned short* __restrict__ wbfs,
    float* __restrict__ gacc)
{
    int idx = blockIdx.x * 256 + threadIdx.x;
    if (idx < 256) gacc[idx] = 0.0f;
    if (idx < 32768) {
        wbfr[idx] = f2bf(w_reduce[idx]);
    } else {
        int k = idx - 32768;
        if (k < 18432) wbfs[k] = f2bf(w_span[k]);
    }
}

// ---------------------------------------------------------------------------
// K1: t2[b][p][o] = sum_c w_reduce[o][c] * x[b][c][p]   (bf16 MFMA 16x16x32)
// Block: 128 o x 64 p (784 blocks, one b each). 4 waves 2x2 over (64o x 32p).
// T3-minimum 2-phase pipeline: chunk k+1 staged via global_load_lds (16B)
// into the alternate buffer WHILE chunk k computes; one barrier per chunk.
// LDS layout: [32 c][16 units of 4 px] fp32, unit index XOR-swizzled
//   U = c*16 + (pq ^ ((c>>1)&7))  (pre-applied on the GLOBAL source address,
//   LDS dest stays linear per the global_load_lds constraint). This makes the
//   frag-build b32 reads 2-way bank-aliased (free) instead of 4-way.
// A-frags direct from global (wbfr bf16, 16B/lane, L1-hot).
// BN partials -> gacc via atomics. t2 stored p-major for K3.
// ---------------------------------------------------------------------------
__global__ __launch_bounds__(256, 3) void reduce_mfma(
    const float* __restrict__ x, const unsigned short* __restrict__ wbfr,
    unsigned short* __restrict__ t2, float* __restrict__ gacc)
{
    __shared__ __align__(16) float xbuf[2][2048];   // 2 x 8 KB chunk buffers
    __shared__ float redp[128][2], redq[128][2];

    const int tid = threadIdx.x;
    const int lane = tid & 63, wv = tid >> 6;
    const int q = lane >> 4, i = lane & 15;
    const int mrow = (wv >> 1) * 64, nrow = (wv & 1) * 32;
    const int blk = blockIdx.x;
    const int b = blk / 49;
    const int p0 = (blk % 49) * 64;

    const float* xb = x + (size_t)b * C_ * HW_ + p0;
    const unsigned short* wb = wbfr + (size_t)(mrow + i) * C_ + q * 8;

    // staging roles: issue e covers LDS units U = e*256 + tid
    int c_s[2], pq_s[2];
    #pragma unroll
    for (int e = 0; e < 2; e++) {
        int U = e * 256 + tid;
        int c = U >> 4;
        c_s[e] = c;
        pq_s[e] = (U & 15) ^ ((c >> 1) & 7);    // inverse swizzle on source
    }
    const int ldsb = (tid & ~63) * 4;           // wave-uniform dst (floats)

    f32x4 acc[4][2] = {};

    // prologue: stage chunk 0
    #pragma unroll
    for (int e = 0; e < 2; e++)
        gload_lds16(xb + (size_t)c_s[e] * HW_ + pq_s[e] * 4,
                    &xbuf[0][e * 1024 + ldsb]);
    __syncthreads();

    #pragma unroll
    for (int ch = 0; ch < 8; ch++) {
        const int cur = ch & 1;
        if (ch < 7) {                            // stage next chunk (async)
            const float* xc = xb + (size_t)(ch + 1) * 32 * HW_;
            #pragma unroll
            for (int e = 0; e < 2; e++)
                gload_lds16(xc + (size_t)c_s[e] * HW_ + pq_s[e] * 4,
                            &xbuf[cur ^ 1][e * 1024 + ldsb]);
        }
        const int c0 = ch * 32;
        s16x8 af[4];
        #pragma unroll
        for (int mt = 0; mt < 4; mt++)
            af[mt] = *(const s16x8*)(wb + (size_t)mt * 16 * C_ + c0);

        const float* bufc = xbuf[cur];
        s16x8 bfr[2];
        #pragma unroll
        for (int nt = 0; nt < 2; nt++) {
            const int p = nrow + nt * 16 + i;
            const int pq = p >> 2, pm = p & 3;
            union { s16x8 v; unsigned u[4]; } Bv;
            #pragma unroll
            for (int k2 = 0; k2 < 4; k2++) {
                int cc = q * 8 + 2 * k2;
                int u0 = cc * 16 + (pq ^ ((cc >> 1) & 7));
                float fa = bufc[u0 * 4 + pm];          // channel cc
                float fb = bufc[u0 * 4 + 64 + pm];     // channel cc+1 (same swz)
                Bv.u[k2] = pkcvt(fa, fb);
            }
            bfr[nt] = Bv.v;
        }
        #pragma unroll
        for (int mt = 0; mt < 4; mt++)
            #pragma unroll
            for (int nt = 0; nt < 2; nt++)
                acc[mt][nt] = __builtin_amdgcn_mfma_f32_16x16x32_bf16(
                    af[mt], bfr[nt], acc[mt][nt], 0, 0, 0);
        __syncthreads();   // drains the async stage; next chunk ready
    }

    // Epilogue: D col=i -> p, row=q*4+reg -> o (4 consecutive o per lane).
    // Store t2[b][p][o] as one dwordx2 per (mt,nt).
    #pragma unroll
    for (int mt = 0; mt < 4; mt++) {
        #pragma unroll
        for (int nt = 0; nt < 2; nt++) {
            int p = p0 + nrow + nt * 16 + i;
            uint2 pr;
            pr.x = pkcvt(acc[mt][nt][0], acc[mt][nt][1]);
            pr.y = pkcvt(acc[mt][nt][2], acc[mt][nt][3]);
            *(uint2*)(t2 + ((size_t)b * HW_ + p) * CR_ + mrow + mt * 16 + q * 4) = pr;
        }
        #pragma unroll
        for (int reg = 0; reg < 4; reg++) {
            float v0 = acc[mt][0][reg], v1 = acc[mt][1][reg];
            float s = v0 + v1;
            float ss = v0 * v0 + v1 * v1;
            #pragma unroll
            for (int m = 1; m < 16; m <<= 1) {
                s  += __shfl_xor(s, m);
                ss += __shfl_xor(ss, m);
            }
            if (i == 0) {
                int o = mrow + mt * 16 + q * 4 + reg;
                redp[o][wv & 1] = s;
                redq[o][wv & 1] = ss;
            }
        }
    }
    __syncthreads();
    if (tid < 128) atomicAdd(&gacc[tid], redp[tid][0] + redp[tid][1]);
    else           atomicAdd(&gacc[tid], redq[tid - 128][0] + redq[tid - 128][1]);
}

// ---------------------------------------------------------------------------
// K3: kern[b][g][kk][p] = sum_o w_span[kk*16+g][o]*relu(bn(t2[b][p][o])) + b
// Block: 144 o2 x 64 p (784 blocks). 4 waves split p 4-way (144 x 16 each).
// Same 2-phase async pipeline. t2 p-major => one 4KB global_load_lds issue
// per chunk, and each lane's whole B-frag is a single ds_read_b128 (the
// plain [p][4 units] layout already spreads lanes uniformly over bank quads).
// BN scale/shift computed per block from gacc (128 rsqrt, free).
// kern stored [b][g][kk][p] so K4's 9 taps are stride-HW_ apart.
// ---------------------------------------------------------------------------
__global__ __launch_bounds__(256, 3) void span_mfma(
    const unsigned short* __restrict__ t2, const unsigned short* __restrict__ wbfs,
    const float* __restrict__ b_span, const float* __restrict__ gacc,
    const float* __restrict__ gamma, const float* __restrict__ beta,
    unsigned short* __restrict__ kern)
{
    __shared__ __align__(16) unsigned short tbuf[2][2048];  // 2 x 4 KB
    __shared__ float scs[128], shs[128], bsp[144];

    const int tid = threadIdx.x;
    const int lane = tid & 63, wv = tid >> 6;
    const int q = lane >> 4, i = lane & 15;
    const int blk = blockIdx.x;
    const int b = blk / 49;
    const int p0 = (blk % 49) * 64;

    if (tid < 128) {
        float s = gacc[tid], ss = gacc[128 + tid];
        const float inv_n = 1.0f / (float)NPOS;
        float mu = s * inv_n;
        float var = ss * inv_n - mu * mu;
        float sc = gamma[tid] * rsqrtf(var + EPS_);
        scs[tid] = sc;
        shs[tid] = beta[tid] - mu * sc;
    }
    if (tid < 144) bsp[tid] = b_span[tid];

    // staging: LDS unit U = tid -> p = U>>2, slot s = U&3 (8 ch each)
    const unsigned short* trow =
        t2 + ((size_t)b * HW_ + p0 + (tid >> 2)) * CR_ + (tid & 3) * 8;
    const int ldsb = (tid & ~63) * 8;           // wave-uniform dst (shorts)
    const int ufr = ((wv * 16 + i) * 4 + q) * 8; // frag read base (shorts)
    const unsigned short* wb = wbfs + (size_t)i * CR_ + q * 8;

    f32x4 acc[9] = {};

    __syncthreads();                              // scs/shs ready
    gload_lds16(trow, &tbuf[0][ldsb]);            // stage chunk 0
    __syncthreads();

    #pragma unroll
    for (int ch = 0; ch < 4; ch++) {
        const int cur = ch & 1;
        if (ch < 3)
            gload_lds16(trow + (ch + 1) * 32, &tbuf[cur ^ 1][ldsb]);

        const int c0 = ch * 32;
        const int cb = c0 + q * 8;
        s16x8 raw = *(const s16x8*)&tbuf[cur][ufr];
        float f[8];
        #pragma unroll
        for (int k = 0; k < 8; k++)
            f[k] = fmaxf(fmaf(bf2f((unsigned short)raw[k]),
                              scs[cb + k], shs[cb + k]), 0.0f);
        union { s16x8 v; unsigned u[4]; } Bv;
        #pragma unroll
        for (int k2 = 0; k2 < 4; k2++) Bv.u[k2] = pkcvt(f[2*k2], f[2*k2+1]);

        #pragma unroll
        for (int mt = 0; mt < 9; mt++) {
            s16x8 af = *(const s16x8*)(wb + (size_t)mt * 16 * CR_ + c0);
            acc[mt] = __builtin_amdgcn_mfma_f32_16x16x32_bf16(af, Bv.v, acc[mt], 0, 0, 0);
        }
        __syncthreads();
    }

    // Epilogue: col=i -> p, row=q*4+reg -> o2 = kk*16+g; remap to [g][kk]
    const int p = p0 + wv * 16 + i;
    #pragma unroll
    for (int mt = 0; mt < 9; mt++) {
        #pragma unroll
        for (int reg = 0; reg < 4; reg++) {
            int o2 = mt * 16 + q * 4 + reg;
            int row = (o2 & 15) * 9 + (o2 >> 4);   // g*9 + kk
            kern[((size_t)b * KKG_ + row) * HW_ + p] = f2bf(acc[mt][reg] + bsp[o2]);
        }
    }
}

// ---------------------------------------------------------------------------
// K4: out[b, g*16+d, p] = sum_kk x[b, g*16+d, p+off(kk)] * kern[b][g][kk][p]
// ---------------------------------------------------------------------------
__global__ __launch_bounds__(256) void involution_apply(
    const float* __restrict__ x, const unsigned short* __restrict__ kern,
    float* __restrict__ out)
{
    int gtid = blockIdx.x * 256 + threadIdx.x;
    int pix = gtid % HW_;
    int bg  = gtid / HW_;
    int g = bg & 15;
    int b = bg >> 4;
    int h = pix / W_;
    int w = pix % W_;

    const unsigned short* kb = kern + ((size_t)(b * G_ + g) * 9) * HW_ + pix;
    float kv[9];
    #pragma unroll
    for (int kk = 0; kk < 9; kk++)
        kv[kk] = bf2f(kb[(size_t)kk * HW_]);

    float acc[16];
    #pragma unroll
    for (int d = 0; d < 16; d++) acc[d] = 0.0f;

    const float* xb = x + (size_t)(b * C_ + g * 16) * HW_;
    #pragma unroll
    for (int di = 0; di < 3; di++) {
        int hh = h + di - 1;
        if (hh < 0 || hh >= W_) continue;
        #pragma unroll
        for (int dj = 0; dj < 3; dj++) {
            int ww = w + dj - 1;
            if (ww < 0 || ww >= W_) continue;
            float kval = kv[di * 3 + dj];
            int off = hh * W_ + ww;
            #pragma unroll
            for (int d = 0; d < 16; d++)
                acc[d] = fmaf(xb[(size_t)d * HW_ + off], kval, acc[d]);
        }
    }
    float* ob = out + (size_t)(b * C_ + g * 16) * HW_ + pix;
    #pragma unroll
    for (int d = 0; d < 16; d++) ob[(size_t)d * HW_] = acc[d];
}

extern "C" void kernel_launch(void* const* d_in, const int* in_sizes, int n_in,
                              void* d_out, int out_size, void* d_ws, size_t ws_size,
                              hipStream_t stream) {
    const float* x        = (const float*)d_in[0];
    const float* w_reduce = (const float*)d_in[1];
    // d_in[2] = b_reduce: unused — per-channel bias cancels exactly in BN.
    const float* gamma    = (const float*)d_in[3];
    const float* beta     = (const float*)d_in[4];
    const float* w_span   = (const float*)d_in[5];
    const float* b_span   = (const float*)d_in[6];
    float* out = (float*)d_out;

    char* wsb = (char*)d_ws;
    unsigned short* t2   = (unsigned short*)(wsb + T2_OFF_B);
    unsigned short* kern = (unsigned short*)(wsb + KERN_OFF_B);
    float*          gacc = (float*)(wsb + GACC_OFF_B);
    unsigned short* wbfr = (unsigned short*)(wsb + WBFR_OFF_B);
    unsigned short* wbfs = (unsigned short*)(wsb + WBFS_OFF_B);

    prep_cast<<<200, 256, 0, stream>>>(w_reduce, w_span, wbfr, wbfs, gacc);
    reduce_mfma<<<NBLK, 256, 0, stream>>>(x, wbfr, t2, gacc);
    span_mfma<<<NBLK, 256, 0, stream>>>(t2, wbfs, b_span, gacc, gamma, beta, kern);
    involution_apply<<<(B_ * G_ * HW_) / 256, 256, 0, stream>>>(x, kern, out);
}